// Round 1
// baseline (653.859 us; speedup 1.0000x reference)
//
#include <hip/hip_runtime.h>
#include <hip/hip_bf16.h>

// ---------- helpers ----------
typedef short short8 __attribute__((ext_vector_type(8)));
typedef float f32x4 __attribute__((ext_vector_type(4)));

__device__ inline unsigned short f2bf(float x) {
  union { float f; unsigned u; } un; un.f = x;
  unsigned r = un.u + 0x7FFFu + ((un.u >> 16) & 1u);
  return (unsigned short)(r >> 16);
}

// ---------- weight prep: WcatT [768][128] bf16 (row n = output col), WgTopT [128][128], bcat[768] ----------
__global__ void prep_weights(const float* __restrict__ Wq, const float* __restrict__ bq,
                             const float* __restrict__ Wk, const float* __restrict__ bk,
                             const float* __restrict__ Wv, const float* __restrict__ bv,
                             const float* __restrict__ Ws, const float* __restrict__ bs,
                             const float* __restrict__ Wsp, const float* __restrict__ bsp,
                             const float* __restrict__ Wg, const float* __restrict__ bg,
                             unsigned short* __restrict__ WcatT, unsigned short* __restrict__ WgTopT,
                             float* __restrict__ bcat) {
  int tid = blockIdx.x * 256 + threadIdx.x;
  if (tid >= 768 * 128) return;
  int n = tid >> 7, k = tid & 127;
  int s = n >> 7, c = n & 127;
  float val;
  if (s == 0) val = Wq[k * 128 + c];
  else if (s == 1) val = Wk[k * 128 + c];
  else if (s == 2) val = Wv[k * 128 + c];
  else if (s == 3) val = Ws[k * 128 + c];
  else if (s == 4) val = Wsp[k * 128 + c];
  else val = Wg[(128 + k) * 128 + c];   // bottom half of Wg (x part of concat)
  WcatT[tid] = f2bf(val);
  if (n < 128) WgTopT[n * 128 + k] = f2bf(Wg[k * 128 + n]);  // top half of Wg, transposed
  if (k == 0) {
    float bv2;
    if (s == 0) bv2 = bq[c]; else if (s == 1) bv2 = bk[c]; else if (s == 2) bv2 = bv[c];
    else if (s == 3) bv2 = bs[c]; else if (s == 4) bv2 = bsp[c]; else bv2 = bg[c];
    bcat[n] = bv2;
  }
}

__global__ void convert_bf16(const float* __restrict__ x, unsigned short* __restrict__ xb, int n4) {
  int i = blockIdx.x * 256 + threadIdx.x;
  if (i < n4) {
    float4 v = ((const float4*)x)[i];
    ushort4 o;
    o.x = f2bf(v.x); o.y = f2bf(v.y); o.z = f2bf(v.z); o.w = f2bf(v.w);
    ((ushort4*)xb)[i] = o;
  }
}

// ---------- CSR build ----------
__global__ void count_deg(const int* __restrict__ dst, int* __restrict__ deg, int E) {
  int i = blockIdx.x * 256 + threadIdx.x;
  if (i < E) atomicAdd(&deg[dst[i]], 1);
}

__global__ __launch_bounds__(1024) void scan_kernel(const int* __restrict__ deg, int* __restrict__ off,
                                                    int* __restrict__ cursor, int n) {
  __shared__ int part[1024];
  int t = threadIdx.x;
  int CH = (n + 1023) / 1024;
  int base = t * CH;
  int s = 0;
  for (int j = 0; j < CH; ++j) { int i = base + j; if (i < n) s += deg[i]; }
  part[t] = s;
  __syncthreads();
  for (int d = 1; d < 1024; d <<= 1) {
    int v = (t >= d) ? part[t - d] : 0;
    __syncthreads();
    part[t] += v;
    __syncthreads();
  }
  int ex = (t == 0) ? 0 : part[t - 1];
  for (int j = 0; j < CH; ++j) {
    int i = base + j;
    if (i < n) { off[i] = ex; cursor[i] = ex; ex += deg[i]; }
  }
  if (t == 1023) off[n] = part[1023];
}

__global__ void scatter_kernel(const int* __restrict__ ei, int* __restrict__ cursor,
                               int* __restrict__ slot, int E) {
  int i = blockIdx.x * 256 + threadIdx.x;
  if (i < E) {
    int d = ei[E + i];  // dst row
    int p = atomicAdd(&cursor[d], 1);
    slot[p] = i;
  }
}

// ---------- bf16 MFMA GEMM: C[M,ldc-slice] = A[M,128] @ BT[Nout,128]^T (+bias) ----------
// A row-major [M,128] bf16; BT row n holds column n of W (128 k-values).
// Block: 256 thr, 4 waves; 128x128 output tile; K=128 in one shot (4 MFMA k-steps).
__global__ __launch_bounds__(256) void gemm_k128(const unsigned short* __restrict__ A,
                                                 const unsigned short* __restrict__ BT,
                                                 const float* __restrict__ bias,
                                                 float* __restrict__ C, int M, int ldc) {
  __shared__ char As[32768];
  __shared__ char Bs[32768];
  int m0 = blockIdx.x * 128;
  int n0 = blockIdx.y * 128;
  int t = threadIdx.x;
  // stage A tile (rows m0..m0+127), XOR-swizzled 16B chunks
  {
    int row = t >> 1;
    int hb = (t & 1) * 128;
    const char* srow = (const char*)(A + (size_t)(m0 + row) * 128);
    bool ok = (m0 + row) < M;
    char* lrow = As + row * 256;
    int sw = (row & 7) << 4;
#pragma unroll
    for (int j = 0; j < 8; ++j) {
      int b = hb + j * 16;
      uint4 val;
      if (ok) val = *(const uint4*)(srow + b);
      else { val.x = 0; val.y = 0; val.z = 0; val.w = 0; }
      *(uint4*)(lrow + (b ^ sw)) = val;
    }
  }
  // stage B tile (rows n0..n0+127 of BT); Nout always multiple of 128
  {
    int row = t >> 1;
    int hb = (t & 1) * 128;
    const char* srow = (const char*)(BT + (size_t)(n0 + row) * 128);
    char* lrow = Bs + row * 256;
    int sw = (row & 7) << 4;
#pragma unroll
    for (int j = 0; j < 8; ++j) {
      int b = hb + j * 16;
      uint4 val = *(const uint4*)(srow + b);
      *(uint4*)(lrow + (b ^ sw)) = val;
    }
  }
  __syncthreads();
  int w = t >> 6, lane = t & 63;
  int lm = lane & 15, hi = lane >> 4;
  f32x4 acc[2][8] = {};
#pragma unroll
  for (int kb = 0; kb < 4; ++kb) {
    int colb = kb * 64 + hi * 16;  // byte offset of this lane's 8 k-elements
    short8 a[2];
#pragma unroll
    for (int rf = 0; rf < 2; ++rf) {
      int row = w * 32 + rf * 16 + lm;
      a[rf] = *(const short8*)(As + row * 256 + (colb ^ ((row & 7) << 4)));
    }
#pragma unroll
    for (int cf = 0; cf < 8; ++cf) {
      int row = cf * 16 + lm;
      short8 b = *(const short8*)(Bs + row * 256 + (colb ^ ((row & 7) << 4)));
      acc[0][cf] = __builtin_amdgcn_mfma_f32_16x16x32_bf16(a[0], b, acc[0][cf], 0, 0, 0);
      acc[1][cf] = __builtin_amdgcn_mfma_f32_16x16x32_bf16(a[1], b, acc[1][cf], 0, 0, 0);
    }
  }
#pragma unroll
  for (int rf = 0; rf < 2; ++rf) {
#pragma unroll
    for (int cf = 0; cf < 8; ++cf) {
      int col = n0 + cf * 16 + lm;
      float bv = bias ? bias[col] : 0.0f;
#pragma unroll
      for (int j = 0; j < 4; ++j) {
        int row = m0 + w * 32 + rf * 16 + hi * 4 + j;
        if (row < M) C[(size_t)row * ldc + col] = acc[rf][cf][j] + bv;
      }
    }
  }
}

// ---------- node-centric online-softmax edge aggregation ----------
// Y: [N,768] = q|k|v|xs|skip|gate_x. One wave = (node, 2 heads). ch = half*64+lane.
__global__ __launch_bounds__(256) void edge_aggregate(const int* __restrict__ slot,
                                                      const int* __restrict__ off,
                                                      const int* __restrict__ edge_index,
                                                      const float* __restrict__ edge_attr,
                                                      const float* __restrict__ We,
                                                      const float* __restrict__ Y,
                                                      float* __restrict__ agg, int Nn) {
  int w = threadIdx.x >> 6, lane = threadIdx.x & 63;
  int node = blockIdx.x * 2 + (w >> 1);
  if (node >= Nn) return;
  int half = w & 1;
  int ch = half * 64 + lane;
  float we[16];
#pragma unroll
  for (int t2 = 0; t2 < 16; ++t2) we[t2] = We[t2 * 128 + ch];
  float q_l = Y[(size_t)node * 768 + ch];
  float m = -INFINITY, den = 0.0f, acc = 0.0f;
  int beg = off[node], end = off[node + 1];
  for (int p = beg; p < end; ++p) {
    int eid = __builtin_amdgcn_readfirstlane(slot[p]);
    int src = __builtin_amdgcn_readfirstlane(edge_index[eid]);  // src row of edge_index
    const float* ar = edge_attr + (size_t)eid * 16;
    float e_l = 0.0f;
#pragma unroll
    for (int t2 = 0; t2 < 16; ++t2) e_l = fmaf(ar[t2], we[t2], e_l);
    const float* srow = Y + (size_t)src * 768;
    float kj = srow[128 + ch] + e_l;
    float prod = q_l * kj;
#pragma unroll
    for (int o = 16; o; o >>= 1) prod += __shfl_xor(prod, o, 32);
    float alpha = prod * 0.17677669529663687f;  // 1/sqrt(32)
    float mn = fmaxf(m, alpha);
    float sc = __expf(m - mn);    // m==-inf -> 0
    float pt = __expf(alpha - mn);
    float vj = srow[256 + ch] + e_l;
    den = den * sc + pt;
    acc = acc * sc + pt * vj;
    m = mn;
  }
  agg[(size_t)node * 128 + ch] = acc / (den + 1e-16f);
}

// ---------- LN1 + GELU ----------
__global__ __launch_bounds__(256) void ln_gelu_kernel(const float* __restrict__ agg,
                                                      const float* __restrict__ Y,
                                                      const float* __restrict__ g1,
                                                      const float* __restrict__ b1,
                                                      float* __restrict__ u,
                                                      unsigned short* __restrict__ ub, int Nn) {
  int w = threadIdx.x >> 6, lane = threadIdx.x & 63;
  int row = blockIdx.x * 4 + w;
  if (row >= Nn) return;
  const float* yrow = Y + (size_t)row * 768 + 384;  // xs segment
  const float* arow = agg + (size_t)row * 128;
  float h0 = arow[lane] + yrow[lane];
  float h1 = arow[lane + 64] + yrow[lane + 64];
  float s = h0 + h1;
#pragma unroll
  for (int o = 32; o; o >>= 1) s += __shfl_xor(s, o, 64);
  float mean = s * (1.0f / 128.0f);
  float d0 = h0 - mean, d1 = h1 - mean;
  float ss = d0 * d0 + d1 * d1;
#pragma unroll
  for (int o = 32; o; o >>= 1) ss += __shfl_xor(ss, o, 64);
  float rs = rsqrtf(ss * (1.0f / 128.0f) + 1e-5f);
  float y0 = d0 * rs * g1[lane] + b1[lane];
  float y1 = d1 * rs * g1[lane + 64] + b1[lane + 64];
  float u0 = 0.5f * y0 * (1.0f + erff(y0 * 0.7071067811865475f));
  float u1 = 0.5f * y1 * (1.0f + erff(y1 * 0.7071067811865475f));
  size_t base = (size_t)row * 128;
  u[base + lane] = u0;
  u[base + lane + 64] = u1;
  ub[base + lane] = f2bf(u0);
  ub[base + lane + 64] = f2bf(u1);
}

// ---------- gate + LN2 -> out ----------
__global__ __launch_bounds__(256) void gate_ln_kernel(const float* __restrict__ gate_u,
                                                      const float* __restrict__ Y,
                                                      const float* __restrict__ u,
                                                      const float* __restrict__ g2,
                                                      const float* __restrict__ b2,
                                                      float* __restrict__ out, int Nn) {
  int w = threadIdx.x >> 6, lane = threadIdx.x & 63;
  int row = blockIdx.x * 4 + w;
  if (row >= Nn) return;
  const float* yrow = Y + (size_t)row * 768;
  size_t base = (size_t)row * 128;
  float z0 = gate_u[base + lane] + yrow[640 + lane];            // gate_x (has bg)
  float z1 = gate_u[base + lane + 64] + yrow[640 + lane + 64];
  float gg0 = 1.0f / (1.0f + __expf(-z0));
  float gg1 = 1.0f / (1.0f + __expf(-z1));
  float u0 = u[base + lane], u1 = u[base + lane + 64];
  float s0 = yrow[512 + lane], s1 = yrow[512 + lane + 64];      // skip
  float h0 = gg0 * u0 + (1.0f - gg0) * s0;
  float h1 = gg1 * u1 + (1.0f - gg1) * s1;
  float s = h0 + h1;
#pragma unroll
  for (int o = 32; o; o >>= 1) s += __shfl_xor(s, o, 64);
  float mean = s * (1.0f / 128.0f);
  float d0 = h0 - mean, d1 = h1 - mean;
  float ss = d0 * d0 + d1 * d1;
#pragma unroll
  for (int o = 32; o; o >>= 1) ss += __shfl_xor(ss, o, 64);
  float rs = rsqrtf(ss * (1.0f / 128.0f) + 1e-5f);
  out[base + lane] = d0 * rs * g2[lane] + b2[lane];
  out[base + lane + 64] = d1 * rs * g2[lane + 64] + b2[lane + 64];
}

// ---------- launch ----------
extern "C" void kernel_launch(void* const* d_in, const int* in_sizes, int n_in,
                              void* d_out, int out_size, void* d_ws, size_t ws_size,
                              hipStream_t stream) {
  const float* x = (const float*)d_in[0];
  const int* edge_index = (const int*)d_in[1];
  const float* edge_attr = (const float*)d_in[2];
  const float* Wq = (const float*)d_in[3];
  const float* bq = (const float*)d_in[4];
  const float* Wk = (const float*)d_in[5];
  const float* bk = (const float*)d_in[6];
  const float* Wv = (const float*)d_in[7];
  const float* bv = (const float*)d_in[8];
  const float* We = (const float*)d_in[9];
  const float* Ws = (const float*)d_in[10];
  const float* bs = (const float*)d_in[11];
  const float* Wsp = (const float*)d_in[12];
  const float* bsp = (const float*)d_in[13];
  const float* Wg = (const float*)d_in[14];
  const float* bg = (const float*)d_in[15];
  const float* g1 = (const float*)d_in[16];
  const float* b1 = (const float*)d_in[17];
  const float* g2 = (const float*)d_in[18];
  const float* b2 = (const float*)d_in[19];

  int Nn = in_sizes[0] / 128;
  int E = in_sizes[1] / 2;

  char* p = (char*)d_ws;
  auto alloc = [&](size_t bytes) -> char* {
    char* r = p;
    p += (bytes + 255) & ~(size_t)255;
    return r;
  };
  float* Y = (float*)alloc((size_t)Nn * 768 * 4);       // q|k|v|xs|skip|gate_x
  float* agg = (float*)alloc((size_t)Nn * 128 * 4);
  float* u = (float*)alloc((size_t)Nn * 128 * 4);
  float* gate_u = (float*)alloc((size_t)Nn * 128 * 4);
  unsigned short* xb = (unsigned short*)alloc((size_t)Nn * 128 * 2);
  unsigned short* ub = (unsigned short*)alloc((size_t)Nn * 128 * 2);
  unsigned short* WcatT = (unsigned short*)alloc(768 * 128 * 2);
  unsigned short* WgTopT = (unsigned short*)alloc(128 * 128 * 2);
  float* bcat = (float*)alloc(768 * 4);
  int* deg = (int*)alloc((size_t)Nn * 4);
  int* off = (int*)alloc((size_t)(Nn + 1) * 4);
  int* cursor = (int*)alloc((size_t)Nn * 4);
  int* slot = (int*)alloc((size_t)E * 4);

  hipMemsetAsync(deg, 0, (size_t)Nn * 4, stream);
  prep_weights<<<(768 * 128 + 255) / 256, 256, 0, stream>>>(Wq, bq, Wk, bk, Wv, bv, Ws, bs,
                                                            Wsp, bsp, Wg, bg, WcatT, WgTopT, bcat);
  convert_bf16<<<((Nn * 128 / 4) + 255) / 256, 256, 0, stream>>>(x, xb, Nn * 128 / 4);
  count_deg<<<(E + 255) / 256, 256, 0, stream>>>(edge_index + E, deg, E);
  scan_kernel<<<1, 1024, 0, stream>>>(deg, off, cursor, Nn);
  scatter_kernel<<<(E + 255) / 256, 256, 0, stream>>>(edge_index, cursor, slot, E);

  dim3 g1g((Nn + 127) / 128, 6);
  gemm_k128<<<g1g, 256, 0, stream>>>(xb, WcatT, bcat, Y, Nn, 768);

  edge_aggregate<<<(Nn + 1) / 2, 256, 0, stream>>>(slot, off, edge_index, edge_attr, We, Y, agg, Nn);

  ln_gelu_kernel<<<(Nn + 3) / 4, 256, 0, stream>>>(agg, Y, g1, b1, u, ub, Nn);

  dim3 g2g((Nn + 127) / 128, 1);
  gemm_k128<<<g2g, 256, 0, stream>>>(ub, WgTopT, nullptr, gate_u, Nn, 128);

  gate_ln_kernel<<<(Nn + 3) / 4, 256, 0, stream>>>(gate_u, Y, u, g2, b2, (float*)d_out, Nn);
}